// Round 5
// baseline (255.886 us; speedup 1.0000x reference)
//
#include <hip/hip_runtime.h>
#include <math.h>

#define SPAT  96
#define IMG   (SPAT*SPAT)        /* 9216    */
#define PLANE (SPAT*SPAT*SPAT)   /* 884736  */
#define CC_CH (PLANE/4)          /* 221184 chunks per cc      */
#define D_CH  (IMG/4)            /* 2304 chunks per (cc,d)    */
#define NCHUNK (64u*CC_CH)       /* 14,155,776 float4 chunks  */
#define KSLOT 3
#define STAGE_F4 (4*16*IMG*KSLOT)            /* 1,769,472 float4 = 28.3 MB */
#define STAGE_BYTES ((size_t)STAGE_F4*16)
#define NROWS (4*IMG)                        /* 36,864 (sb,d,h) rows */
#define WS_NEED (STAGE_BYTES + (size_t)NROWS*4)

/* fallback half-tile kernel params */
#define HROWS 48
#define HCHUNK (HROWS*24)

// ---------------------------------------------------------------------------
// 4x4 matrix inverse (adjugate)
// ---------------------------------------------------------------------------
__device__ inline void invert4(const float m[16], float inv[16]) {
    inv[0]  =  m[5]*m[10]*m[15] - m[5]*m[11]*m[14] - m[9]*m[6]*m[15] + m[9]*m[7]*m[14] + m[13]*m[6]*m[11] - m[13]*m[7]*m[10];
    inv[4]  = -m[4]*m[10]*m[15] + m[4]*m[11]*m[14] + m[8]*m[6]*m[15] - m[8]*m[7]*m[14] - m[12]*m[6]*m[11] + m[12]*m[7]*m[10];
    inv[8]  =  m[4]*m[9]*m[15]  - m[4]*m[11]*m[13] - m[8]*m[5]*m[15] + m[8]*m[7]*m[13] + m[12]*m[5]*m[11] - m[12]*m[7]*m[9];
    inv[12] = -m[4]*m[9]*m[14]  + m[4]*m[10]*m[13] + m[8]*m[5]*m[14] - m[8]*m[6]*m[13] - m[12]*m[5]*m[10] + m[12]*m[6]*m[9];
    inv[1]  = -m[1]*m[10]*m[15] + m[1]*m[11]*m[14] + m[9]*m[2]*m[15] - m[9]*m[3]*m[14] - m[13]*m[2]*m[11] + m[13]*m[3]*m[10];
    inv[5]  =  m[0]*m[10]*m[15] - m[0]*m[11]*m[14] - m[8]*m[2]*m[15] + m[8]*m[3]*m[14] + m[12]*m[2]*m[11] - m[12]*m[3]*m[10];
    inv[9]  = -m[0]*m[9]*m[15]  + m[0]*m[11]*m[13] + m[8]*m[1]*m[15] - m[8]*m[3]*m[13] - m[12]*m[1]*m[11] + m[12]*m[3]*m[9];
    inv[13] =  m[0]*m[9]*m[14]  - m[0]*m[10]*m[13] - m[8]*m[1]*m[14] + m[8]*m[2]*m[13] + m[12]*m[1]*m[10] - m[12]*m[2]*m[9];
    inv[2]  =  m[1]*m[6]*m[15]  - m[1]*m[7]*m[14]  - m[5]*m[2]*m[15] + m[5]*m[3]*m[14] + m[13]*m[2]*m[7]  - m[13]*m[3]*m[6];
    inv[6]  = -m[0]*m[6]*m[15]  + m[0]*m[7]*m[14]  + m[4]*m[2]*m[15] - m[4]*m[3]*m[14] - m[12]*m[2]*m[7]  + m[12]*m[3]*m[6];
    inv[10] =  m[0]*m[5]*m[15]  - m[0]*m[7]*m[13]  - m[4]*m[1]*m[15] + m[4]*m[3]*m[13] + m[12]*m[1]*m[7]  - m[12]*m[3]*m[5];
    inv[14] = -m[0]*m[5]*m[14]  + m[0]*m[6]*m[13]  + m[4]*m[1]*m[14] - m[4]*m[2]*m[13] - m[12]*m[1]*m[6]  + m[12]*m[2]*m[5];
    inv[3]  = -m[1]*m[6]*m[11]  + m[1]*m[7]*m[10]  + m[5]*m[2]*m[11] - m[5]*m[3]*m[10] - m[9]*m[2]*m[7]   + m[9]*m[3]*m[6];
    inv[7]  =  m[0]*m[6]*m[11]  - m[0]*m[7]*m[10]  - m[4]*m[2]*m[11] + m[4]*m[3]*m[10] + m[8]*m[2]*m[7]   - m[8]*m[3]*m[6];
    inv[11] = -m[0]*m[5]*m[11]  + m[0]*m[7]*m[9]   + m[4]*m[1]*m[11] - m[4]*m[3]*m[9]  - m[8]*m[1]*m[7]   + m[8]*m[3]*m[5];
    inv[15] =  m[0]*m[5]*m[10]  - m[0]*m[6]*m[9]   - m[4]*m[1]*m[10] + m[4]*m[2]*m[9]  + m[8]*m[1]*m[6]   - m[8]*m[2]*m[5];
    float det  = m[0]*inv[0] + m[1]*inv[4] + m[2]*inv[8] + m[3]*inv[12];
    float rdet = 1.0f / det;
    for (int i = 0; i < 16; ++i) inv[i] *= rdet;
}

__device__ inline void fold_affine(const float* __restrict__ aff_in, int sb,
                                   float M[12]) {
    float A[16];
    #pragma unroll
    for (int i = 0; i < 16; ++i) A[i] = aff_in[sb * 16 + i];
    #pragma unroll
    for (int j = 0; j < 3; ++j) {        // column-normalize by zooms
        float z = sqrtf(A[0*4+j]*A[0*4+j] + A[1*4+j]*A[1*4+j] + A[2*4+j]*A[2*4+j]);
        float rz = 1.0f / z;
        #pragma unroll
        for (int i = 0; i < 4; ++i) A[i*4+j] *= rz;
    }
    float inv[16];
    invert4(A, inv);
    #pragma unroll
    for (int r = 0; r < 3; ++r) {
        float T0 = inv[r*4+0], T1 = inv[r*4+1], T2 = inv[r*4+2], T3 = inv[r*4+3];
        // i_r = T0*w + T1*h + T2*d + [-47.5*(T0+T1+T2) + 48*T3 + 47.5]
        M[r*4+0] = T0;
        M[r*4+1] = T1;
        M[r*4+2] = T2;
        M[r*4+3] = -47.5f * (T0 + T1 + T2) + 48.0f * T3 + 47.5f;
    }
}

// ---------------------------------------------------------------------------
// Prep kernel: one thread per (sb,d,h) row. Computes the contributing chunk
// interval [qlo,qhi] (row table) and composes the <=3 slab chunks for all
// 16 channels of sb into compact staging. Weights/indices are shared across
// channels (the key factorization). Overflow rows (>KSLOT chunks; never for
// near-identity affines) are written directly to out; stream kernel skips.
// grid (96,4) x 128 threads.
// ---------------------------------------------------------------------------
__global__ __launch_bounds__(128) void prep_kernel(
        const float* __restrict__ xin,   // [2,32,96,96]
        const float* __restrict__ aff_in,// [2,2,4,4]
        float4* __restrict__ stage,      // [4sb][16ct][96d][96h][KSLOT]
        unsigned* __restrict__ rowinfo,  // [4sb][96d][96h]
        float* __restrict__ outp) {      // [2,32,96,96,96]
    const int tid = (int)threadIdx.x;
    if (tid >= SPAT) return;
    const int d  = blockIdx.x;           // 0..95
    const int sb = blockIdx.y;           // 0..3
    const int h  = tid;

    float M[12];
    fold_affine(aff_in, sb, M);
    const float Mxw = M[0], Mxh = M[1], Mxd = M[2],  Mx0 = M[3];
    const float Myw = M[4], Myh = M[5], Myd = M[6],  My0 = M[7];
    const float Mzw = M[8], Mzh = M[9], Mzd = M[10], Mz0 = M[11];

    const float fh = (float)h, fd = (float)d;
    const float bx = Mxh * fh + Mxd * fd + Mx0;

    int wlo, whi;
    if (fabsf(Mxw) > 1e-6f) {
        float rMxw = 1.0f / Mxw;
        float w1 = (47.0f - bx) * rMxw;
        float w2 = (49.0f - bx) * rMxw;
        float wmin = fminf(w1, w2), wmax = fmaxf(w1, w2);
        wlo = max((int)ceilf(wmin), 0);
        whi = min((int)floorf(wmax), SPAT - 1);
    } else {
        bool in = fabsf(bx - 48.0f) < 1.0f;
        wlo = in ? 0 : 1;
        whi = in ? SPAT - 1 : 0;
    }

    const int rix = (sb * SPAT + d) * SPAT + h;
    if (wlo > whi) { rowinfo[rix] = 0xFFu; return; }
    const int qlo = wlo >> 2, qhi = whi >> 2;
    const bool ovf = (qhi - qlo + 1) > KSLOT;
    rowinfo[rix] = (unsigned)qlo | ((unsigned)qhi << 8) | (ovf ? 0x10000u : 0u);

    const int s = sb >> 1, b = sb & 1;
    const float* imgbase = xin + (size_t)(b * 32 + s * 16) * IMG;
    const float by = Myh * fh + Myd * fd + My0;
    const float bz = Mzh * fh + Mzd * fd + Mz0;

    for (int q = qlo; q <= qhi; ++q) {
        float wt[4][4];
        int   of[4][4];
        #pragma unroll
        for (int j = 0; j < 4; ++j) {
            float fw = (float)(4 * q + j);
            float ix = Mxw * fw + bx;
            float wx = 1.0f - fabsf(ix - 48.0f);
            if (wx > 0.0f) {
                float iy = Myw * fw + by;
                float iz = Mzw * fw + bz;
                float yf = floorf(iy), zf = floorf(iz);
                float fy = iy - yf,    fz = iz - zf;
                int y0 = (int)yf, z0 = (int)zf;
                bool vy0 = (y0 >= 0)  & (y0 <  SPAT);
                bool vy1 = (y0 >= -1) & (y0 <  SPAT - 1);
                bool vz0 = (z0 >= 0)  & (z0 <  SPAT);
                bool vz1 = (z0 >= -1) & (z0 <  SPAT - 1);
                int y0c = min(max(y0, 0),     SPAT - 1);
                int y1c = min(max(y0 + 1, 0), SPAT - 1);
                int z0c = min(max(z0, 0),     SPAT - 1);
                int z1c = min(max(z0 + 1, 0), SPAT - 1);
                float wy0 = 1.0f - fy, wy1 = fy;
                float wz0 = 1.0f - fz, wz1 = fz;
                wt[j][0] = wx * wz0 * wy0 * ((vz0 & vy0) ? 1.0f : 0.0f);
                wt[j][1] = wx * wz0 * wy1 * ((vz0 & vy1) ? 1.0f : 0.0f);
                wt[j][2] = wx * wz1 * wy0 * ((vz1 & vy0) ? 1.0f : 0.0f);
                wt[j][3] = wx * wz1 * wy1 * ((vz1 & vy1) ? 1.0f : 0.0f);
                of[j][0] = z0c * SPAT + y0c;  of[j][1] = z0c * SPAT + y1c;
                of[j][2] = z1c * SPAT + y0c;  of[j][3] = z1c * SPAT + y1c;
            } else {
                wt[j][0] = wt[j][1] = wt[j][2] = wt[j][3] = 0.0f;
                of[j][0] = of[j][1] = of[j][2] = of[j][3] = 0;
            }
        }
        if (!ovf) {
            const int k = q - qlo;
            #pragma unroll
            for (int ct = 0; ct < 16; ++ct) {
                const float* ic = imgbase + (size_t)ct * IMG;
                float4 v;
                v.x = wt[0][0]*ic[of[0][0]] + wt[0][1]*ic[of[0][1]] + wt[0][2]*ic[of[0][2]] + wt[0][3]*ic[of[0][3]];
                v.y = wt[1][0]*ic[of[1][0]] + wt[1][1]*ic[of[1][1]] + wt[1][2]*ic[of[1][2]] + wt[1][3]*ic[of[1][3]];
                v.z = wt[2][0]*ic[of[2][0]] + wt[2][1]*ic[of[2][1]] + wt[2][2]*ic[of[2][2]] + wt[2][3]*ic[of[2][3]];
                v.w = wt[3][0]*ic[of[3][0]] + wt[3][1]*ic[of[3][1]] + wt[3][2]*ic[of[3][2]] + wt[3][3]*ic[of[3][3]];
                stage[((size_t)(sb * 16 + ct) * IMG + (size_t)d * SPAT + h) * KSLOT + k] = v;
            }
        } else {   // pathological interval: write output directly (rare/never)
            #pragma unroll
            for (int ct = 0; ct < 16; ++ct) {
                const float* ic = imgbase + (size_t)ct * IMG;
                float4 v;
                v.x = wt[0][0]*ic[of[0][0]] + wt[0][1]*ic[of[0][1]] + wt[0][2]*ic[of[0][2]] + wt[0][3]*ic[of[0][3]];
                v.y = wt[1][0]*ic[of[1][0]] + wt[1][1]*ic[of[1][1]] + wt[1][2]*ic[of[1][2]] + wt[1][3]*ic[of[1][3]];
                v.z = wt[2][0]*ic[of[2][0]] + wt[2][1]*ic[of[2][1]] + wt[2][2]*ic[of[2][2]] + wt[2][3]*ic[of[2][3]];
                v.w = wt[3][0]*ic[of[3][0]] + wt[3][1]*ic[of[3][1]] + wt[3][2]*ic[of[3][2]] + wt[3][3]*ic[of[3][3]];
                *reinterpret_cast<float4*>(outp
                    + (size_t)(b * 32 + s * 16 + ct) * PLANE
                    + ((size_t)d * SPAT + h) * SPAT + 4 * q) = v;
            }
        }
    }
}

// ---------------------------------------------------------------------------
// Stream kernel: fill-identical grid-stride pass. Per float4 chunk: decode
// (magic-mul divides), L2-hot row-table load, predicate, optional staged
// read, unconditional full-wave store (zero or value). No barriers, no LDS,
// ~20 VGPR. Every 128B line written exactly once with final content.
// ---------------------------------------------------------------------------
__global__ __launch_bounds__(256) void stream_kernel(
        const float4* __restrict__ stage,
        const unsigned* __restrict__ rowinfo,
        float4* __restrict__ out) {
    size_t i = (size_t)blockIdx.x * 256 + threadIdx.x;
    const size_t stride = (size_t)gridDim.x * 256;
    for (; i < (size_t)NCHUNK; i += stride) {
        unsigned ii = (unsigned)i;
        unsigned cc = ii / CC_CH;            // magic-mul
        unsigned r1 = ii - cc * CC_CH;
        unsigned dd = r1 / D_CH;
        unsigned r2 = r1 - dd * D_CH;
        unsigned hh = r2 / 24u;
        unsigned q  = r2 - hh * 24u;
        unsigned sb = ((cc >> 4) & 1u) * 2u + (cc >> 5);
        unsigned info = rowinfo[(sb * SPAT + dd) * SPAT + hh];
        unsigned qlo = info & 0xFFu;
        unsigned qhi = (info >> 8) & 0xFFu;
        bool ins = (q >= qlo) && (q <= qhi);
        bool ovf = (info >> 16) != 0u;
        float4 v = make_float4(0.f, 0.f, 0.f, 0.f);
        if (ins && !ovf)
            v = stage[((size_t)(sb * 16u + (cc & 15u)) * IMG
                       + (size_t)dd * SPAT + hh) * KSLOT + (q - qlo)];
        if (!(ins && ovf))                    // full-wave store unless prep
            out[i] = v;                       // already wrote (ovf row)
    }
}

// ---------------------------------------------------------------------------
// Fallback (ws too small): R4 half-tile LDS-compose kernel, verbatim.
// ---------------------------------------------------------------------------
__global__ __launch_bounds__(256, 4) void fused4_kernel(
        const float* __restrict__ xin,
        const float* __restrict__ aff_in,
        float4* __restrict__ out) {
    __shared__ float4 tile[HCHUNK];
    const int tid = (int)threadIdx.x;
    const int dh2 = blockIdx.x;
    const int d   = dh2 >> 1;
    const int hh  = dh2 & 1;
    const int cc  = blockIdx.y;
    const int b   = cc >> 5;
    const int s   = (cc >> 4) & 1;
    const int sb  = s * 2 + b;

    float M[12];
    fold_affine(aff_in, sb, M);
    const float Mxw = M[0], Mxh = M[1], Mxd = M[2],  Mx0 = M[3];
    const float Myw = M[4], Myh = M[5], Myd = M[6],  My0 = M[7];
    const float Mzw = M[8], Mzh = M[9], Mzd = M[10], Mz0 = M[11];

    const float* img = xin + (size_t)cc * IMG;

    float tv[16];
    float bx = 0.f, by = 0.f, bz = 0.f;
    int   rr = 0, myq = 0, fqlo = 0, fqhi = -1;
    bool  act = false;
    if (tid < 2 * HROWS) {
        rr = tid >> 1;
        const int k = tid & 1;
        const int h = hh * HROWS + rr;
        const float fh = (float)h, fd = (float)d;
        bx = Mxh * fh + Mxd * fd + Mx0;
        by = Myh * fh + Myd * fd + My0;
        bz = Mzh * fh + Mzd * fd + Mz0;

        int wlo, whi;
        if (fabsf(Mxw) > 1e-6f) {
            float rMxw = 1.0f / Mxw;
            float w1 = (47.0f - bx) * rMxw;
            float w2 = (49.0f - bx) * rMxw;
            float wmin = fminf(w1, w2), wmax = fmaxf(w1, w2);
            wlo = max((int)ceilf(wmin), 0);
            whi = min((int)floorf(wmax), SPAT - 1);
        } else {
            bool in = fabsf(bx - 48.0f) < 1.0f;
            wlo = in ? 0 : 1;
            whi = in ? SPAT - 1 : 0;
        }
        const int qlo = wlo >> 2, qhi = whi >> 2;
        myq = qlo + k;
        if (wlo <= whi && myq <= qhi) {
            act = true;
            #pragma unroll
            for (int j = 0; j < 4; ++j) {
                float fw = (float)(4 * myq + j);
                float ix = Mxw * fw + bx;
                float wx = 1.0f - fabsf(ix - 48.0f);
                if (wx > 0.0f) {
                    float iy = Myw * fw + by;
                    float iz = Mzw * fw + bz;
                    int y0 = (int)floorf(iy), z0 = (int)floorf(iz);
                    int y0c = min(max(y0, 0),     SPAT - 1);
                    int y1c = min(max(y0 + 1, 0), SPAT - 1);
                    int z0c = min(max(z0, 0),     SPAT - 1);
                    int z1c = min(max(z0 + 1, 0), SPAT - 1);
                    tv[4*j+0] = img[z0c * SPAT + y0c];
                    tv[4*j+1] = img[z0c * SPAT + y1c];
                    tv[4*j+2] = img[z1c * SPAT + y0c];
                    tv[4*j+3] = img[z1c * SPAT + y1c];
                } else {
                    tv[4*j+0] = 0.f; tv[4*j+1] = 0.f;
                    tv[4*j+2] = 0.f; tv[4*j+3] = 0.f;
                }
            }
        }
        if (k == 1 && wlo <= whi) { fqlo = qlo + 2; fqhi = qhi; }
    }

    const float4 z4 = make_float4(0.f, 0.f, 0.f, 0.f);
    #pragma unroll
    for (int i = tid; i < HCHUNK; i += 256) tile[i] = z4;

    __syncthreads();

    if (act) {
        float vv[4];
        #pragma unroll
        for (int j = 0; j < 4; ++j) {
            float fw = (float)(4 * myq + j);
            float ix = Mxw * fw + bx;
            float wx = 1.0f - fabsf(ix - 48.0f);
            float r = 0.0f;
            if (wx > 0.0f) {
                float iy = Myw * fw + by;
                float iz = Mzw * fw + bz;
                float yf = floorf(iy), zf = floorf(iz);
                float fy = iy - yf,    fz = iz - zf;
                int y0 = (int)yf, z0 = (int)zf;
                bool vy0 = (y0 >= 0)  & (y0 <  SPAT);
                bool vy1 = (y0 >= -1) & (y0 <  SPAT - 1);
                bool vz0 = (z0 >= 0)  & (z0 <  SPAT);
                bool vz1 = (z0 >= -1) & (z0 <  SPAT - 1);
                float wy0 = 1.0f - fy, wy1 = fy;
                float wz0 = 1.0f - fz, wz1 = fz;
                float w00 = wx * wz0 * wy0 * ((vz0 & vy0) ? 1.0f : 0.0f);
                float w01 = wx * wz0 * wy1 * ((vz0 & vy1) ? 1.0f : 0.0f);
                float w10 = wx * wz1 * wy0 * ((vz1 & vy0) ? 1.0f : 0.0f);
                float w11 = wx * wz1 * wy1 * ((vz1 & vy1) ? 1.0f : 0.0f);
                r = w00 * tv[4*j+0] + w01 * tv[4*j+1]
                  + w10 * tv[4*j+2] + w11 * tv[4*j+3];
            }
            vv[j] = r;
        }
        tile[rr * 24 + myq] = make_float4(vv[0], vv[1], vv[2], vv[3]);
    }
    for (int q = fqlo; q <= fqhi; ++q) {
        float vv[4];
        #pragma unroll
        for (int j = 0; j < 4; ++j) {
            float fw = (float)(4 * q + j);
            float ix = Mxw * fw + bx;
            float wx = 1.0f - fabsf(ix - 48.0f);
            float r = 0.0f;
            if (wx > 0.0f) {
                float iy = Myw * fw + by;
                float iz = Mzw * fw + bz;
                float yf = floorf(iy), zf = floorf(iz);
                float fy = iy - yf,    fz = iz - zf;
                int y0 = (int)yf, z0 = (int)zf;
                bool vy0 = (y0 >= 0)  & (y0 <  SPAT);
                bool vy1 = (y0 >= -1) & (y0 <  SPAT - 1);
                bool vz0 = (z0 >= 0)  & (z0 <  SPAT);
                bool vz1 = (z0 >= -1) & (z0 <  SPAT - 1);
                int y0c = min(max(y0, 0),     SPAT - 1);
                int y1c = min(max(y0 + 1, 0), SPAT - 1);
                int z0c = min(max(z0, 0),     SPAT - 1);
                int z1c = min(max(z0 + 1, 0), SPAT - 1);
                float wy0 = 1.0f - fy, wy1 = fy;
                float wz0 = 1.0f - fz, wz1 = fz;
                float w00 = wx * wz0 * wy0 * ((vz0 & vy0) ? 1.0f : 0.0f);
                float w01 = wx * wz0 * wy1 * ((vz0 & vy1) ? 1.0f : 0.0f);
                float w10 = wx * wz1 * wy0 * ((vz1 & vy0) ? 1.0f : 0.0f);
                float w11 = wx * wz1 * wy1 * ((vz1 & vy1) ? 1.0f : 0.0f);
                r = w00 * img[z0c * SPAT + y0c] + w01 * img[z0c * SPAT + y1c]
                  + w10 * img[z1c * SPAT + y0c] + w11 * img[z1c * SPAT + y1c];
            }
            vv[j] = r;
        }
        tile[rr * 24 + q] = make_float4(vv[0], vv[1], vv[2], vv[3]);
    }

    __syncthreads();

    float4* op = out + ((size_t)cc * (PLANE / 4) + (size_t)d * (IMG / 4)
                        + (size_t)hh * HCHUNK);
    #pragma unroll
    for (int i = tid; i < HCHUNK; i += 256) op[i] = tile[i];
}

extern "C" void kernel_launch(void* const* d_in, const int* in_sizes, int n_in,
                              void* d_out, int out_size, void* d_ws, size_t ws_size,
                              hipStream_t stream) {
    const float* x   = (const float*)d_in[0];   // [2,32,96,96] fp32
    const float* aff = (const float*)d_in[1];   // [2,2,4,4]    fp32
    float* out = (float*)d_out;                 // [2,32,96,96,96] fp32

    if (d_ws != nullptr && ws_size >= WS_NEED) {
        float4*   stage   = (float4*)d_ws;
        unsigned* rowinfo = (unsigned*)((char*)d_ws + STAGE_BYTES);
        // 1) tiny prep: row table + compact staged slab values (+rare direct)
        dim3 pgrid(SPAT, 4);
        prep_kernel<<<pgrid, 128, 0, stream>>>(x, aff, stage, rowinfo, out);
        // 2) fill-identical streaming pass: one full-wave store per chunk
        stream_kernel<<<4096, 256, 0, stream>>>(stage, rowinfo, (float4*)out);
    } else {
        dim3 grid(2 * SPAT, 64);
        fused4_kernel<<<grid, 256, 0, stream>>>(x, aff, (float4*)out);
    }
}

// Round 6
// 241.604 us; speedup vs baseline: 1.0591x; 1.0591x over previous
//
#include <hip/hip_runtime.h>
#include <math.h>

#define SPAT  96
#define IMG   (SPAT*SPAT)        /* 9216    */
#define PLANE (SPAT*SPAT*SPAT)   /* 884736  */
#define KSLOT 3
#define STAGE_F4 ((size_t)4*16*IMG*KSLOT)    /* 1,769,472 float4 = 28.3 MB */
#define STAGE_BYTES (STAGE_F4*16)
#define NROWS (4*IMG)                        /* 36,864 (sb,d,h) rows */
#define WS_NEED (STAGE_BYTES + (size_t)NROWS*4)

/* fallback half-tile kernel params */
#define HROWS 48
#define HCHUNK (HROWS*24)

// ---------------------------------------------------------------------------
// 4x4 matrix inverse (adjugate)
// ---------------------------------------------------------------------------
__device__ inline void invert4(const float m[16], float inv[16]) {
    inv[0]  =  m[5]*m[10]*m[15] - m[5]*m[11]*m[14] - m[9]*m[6]*m[15] + m[9]*m[7]*m[14] + m[13]*m[6]*m[11] - m[13]*m[7]*m[10];
    inv[4]  = -m[4]*m[10]*m[15] + m[4]*m[11]*m[14] + m[8]*m[6]*m[15] - m[8]*m[7]*m[14] - m[12]*m[6]*m[11] + m[12]*m[7]*m[10];
    inv[8]  =  m[4]*m[9]*m[15]  - m[4]*m[11]*m[13] - m[8]*m[5]*m[15] + m[8]*m[7]*m[13] + m[12]*m[5]*m[11] - m[12]*m[7]*m[9];
    inv[12] = -m[4]*m[9]*m[14]  + m[4]*m[10]*m[13] + m[8]*m[5]*m[14] - m[8]*m[6]*m[13] - m[12]*m[5]*m[10] + m[12]*m[6]*m[9];
    inv[1]  = -m[1]*m[10]*m[15] + m[1]*m[11]*m[14] + m[9]*m[2]*m[15] - m[9]*m[3]*m[14] - m[13]*m[2]*m[11] + m[13]*m[3]*m[10];
    inv[5]  =  m[0]*m[10]*m[15] - m[0]*m[11]*m[14] - m[8]*m[2]*m[15] + m[8]*m[3]*m[14] + m[12]*m[2]*m[11] - m[12]*m[3]*m[10];
    inv[9]  = -m[0]*m[9]*m[15]  + m[0]*m[11]*m[13] + m[8]*m[1]*m[15] - m[8]*m[3]*m[13] - m[12]*m[1]*m[11] + m[12]*m[3]*m[9];
    inv[13] =  m[0]*m[9]*m[14]  - m[0]*m[10]*m[13] - m[8]*m[1]*m[14] + m[8]*m[2]*m[13] + m[12]*m[1]*m[10] - m[12]*m[2]*m[9];
    inv[2]  =  m[1]*m[6]*m[15]  - m[1]*m[7]*m[14]  - m[5]*m[2]*m[15] + m[5]*m[3]*m[14] + m[13]*m[2]*m[7]  - m[13]*m[3]*m[6];
    inv[6]  = -m[0]*m[6]*m[15]  + m[0]*m[7]*m[14]  + m[4]*m[2]*m[15] - m[4]*m[3]*m[14] - m[12]*m[2]*m[7]  + m[12]*m[3]*m[6];
    inv[10] =  m[0]*m[5]*m[15]  - m[0]*m[7]*m[13]  - m[4]*m[1]*m[15] + m[4]*m[3]*m[13] + m[12]*m[1]*m[7]  - m[12]*m[3]*m[5];
    inv[14] = -m[0]*m[5]*m[14]  + m[0]*m[6]*m[13]  + m[4]*m[1]*m[14] - m[4]*m[2]*m[13] - m[12]*m[1]*m[6]  + m[12]*m[2]*m[5];
    inv[3]  = -m[1]*m[6]*m[11]  + m[1]*m[7]*m[10]  + m[5]*m[2]*m[11] - m[5]*m[3]*m[10] - m[9]*m[2]*m[7]   + m[9]*m[3]*m[6];
    inv[7]  =  m[0]*m[6]*m[11]  - m[0]*m[7]*m[10]  - m[4]*m[2]*m[11] + m[4]*m[3]*m[10] + m[8]*m[2]*m[7]   - m[8]*m[3]*m[6];
    inv[11] = -m[0]*m[5]*m[11]  + m[0]*m[7]*m[9]   + m[4]*m[1]*m[11] - m[4]*m[3]*m[9]  - m[8]*m[1]*m[7]   + m[8]*m[3]*m[5];
    inv[15] =  m[0]*m[5]*m[10]  - m[0]*m[6]*m[9]   - m[4]*m[1]*m[10] + m[4]*m[2]*m[9]  + m[8]*m[1]*m[6]   - m[8]*m[2]*m[5];
    float det  = m[0]*inv[0] + m[1]*inv[4] + m[2]*inv[8] + m[3]*inv[12];
    float rdet = 1.0f / det;
    for (int i = 0; i < 16; ++i) inv[i] *= rdet;
}

__device__ inline void fold_affine(const float* __restrict__ aff_in, int sb,
                                   float M[12]) {
    float A[16];
    #pragma unroll
    for (int i = 0; i < 16; ++i) A[i] = aff_in[sb * 16 + i];
    #pragma unroll
    for (int j = 0; j < 3; ++j) {        // column-normalize by zooms
        float z = sqrtf(A[0*4+j]*A[0*4+j] + A[1*4+j]*A[1*4+j] + A[2*4+j]*A[2*4+j]);
        float rz = 1.0f / z;
        #pragma unroll
        for (int i = 0; i < 4; ++i) A[i*4+j] *= rz;
    }
    float inv[16];
    invert4(A, inv);
    #pragma unroll
    for (int r = 0; r < 3; ++r) {
        float T0 = inv[r*4+0], T1 = inv[r*4+1], T2 = inv[r*4+2], T3 = inv[r*4+3];
        // i_r = T0*w + T1*h + T2*d + [-47.5*(T0+T1+T2) + 48*T3 + 47.5]
        M[r*4+0] = T0;
        M[r*4+1] = T1;
        M[r*4+2] = T2;
        M[r*4+3] = -47.5f * (T0 + T1 + T2) + 48.0f * T3 + 47.5f;
    }
}

// ---------------------------------------------------------------------------
// prep2: one thread per (sb,ct,d,h) row-channel. n = ((sb*16+ct)*96+d)*96+h,
// h innermost -> lanes of a wave share (sb,ct,d), consecutive h: gathers have
// good locality, stage writes are contiguous-per-wave (L2 merges full lines).
// Each thread: fold (regs, redundant), interval, <=3 chunks x 16 gathers
// (all independent, L2-resident xin), compose into stage. ct==0 writes the
// rowinfo word. Overflow rows (>KSLOT chunks; never for near-identity
// affines) are composed directly into out; stream2 skips those chunks.
// 589,824 threads = 2304 blocks x 256 -> 36 waves/CU, latency hidden.
// ---------------------------------------------------------------------------
__global__ __launch_bounds__(256) void prep2_kernel(
        const float* __restrict__ xin,   // [2,32,96,96]
        const float* __restrict__ aff_in,// [2,2,4,4]
        float4* __restrict__ stage,      // [4sb][16ct][96d][96h][KSLOT]
        unsigned* __restrict__ rowinfo,  // [4sb][96d][96h]
        float* __restrict__ outp) {      // [2,32,96,96,96]
    const int n  = (int)blockIdx.x * 256 + (int)threadIdx.x;  // exact grid
    const int h  = n % SPAT;
    const int t1 = n / SPAT;
    const int d  = t1 % SPAT;
    const int t2 = t1 / SPAT;            // sb*16 + ct
    const int ct = t2 & 15;
    const int sb = t2 >> 4;
    const int s  = sb >> 1, b = sb & 1;

    float M[12];
    fold_affine(aff_in, sb, M);
    const float Mxw = M[0], Mxh = M[1], Mxd = M[2],  Mx0 = M[3];
    const float Myw = M[4], Myh = M[5], Myd = M[6],  My0 = M[7];
    const float Mzw = M[8], Mzh = M[9], Mzd = M[10], Mz0 = M[11];

    const float fh = (float)h, fd = (float)d;
    const float bx = Mxh * fh + Mxd * fd + Mx0;

    int wlo, whi;
    if (fabsf(Mxw) > 1e-6f) {
        float rMxw = 1.0f / Mxw;
        float w1 = (47.0f - bx) * rMxw;
        float w2 = (49.0f - bx) * rMxw;
        float wmin = fminf(w1, w2), wmax = fmaxf(w1, w2);
        wlo = max((int)ceilf(wmin), 0);
        whi = min((int)floorf(wmax), SPAT - 1);
    } else {
        bool in = fabsf(bx - 48.0f) < 1.0f;
        wlo = in ? 0 : 1;
        whi = in ? SPAT - 1 : 0;
    }
    const int qlo = wlo >> 2, qhi = whi >> 2;
    const bool empty = (wlo > whi);
    const bool ovf = !empty && ((qhi - qlo + 1) > KSLOT);

    if (ct == 0) {
        const int rix = (sb * SPAT + d) * SPAT + h;
        rowinfo[rix] = empty ? 0xFFu
            : ((unsigned)qlo | ((unsigned)qhi << 8) | (ovf ? 0x10000u : 0u));
    }
    if (empty) return;

    const int c_glob = b * 32 + s * 16 + ct;          // output/input channel
    const float* img = xin + (size_t)c_glob * IMG;

    for (int q = qlo; q <= qhi; ++q) {
        float vv[4];
        #pragma unroll
        for (int j = 0; j < 4; ++j) {
            float fw = (float)(4 * q + j);
            float ix = Mxw * fw + bx;
            float wx = 1.0f - fabsf(ix - 48.0f);
            float r = 0.0f;
            if (wx > 0.0f) {
                float by = Myh * fh + Myd * fd + My0;
                float bz = Mzh * fh + Mzd * fd + Mz0;
                float iy = Myw * fw + by;
                float iz = Mzw * fw + bz;
                float yf = floorf(iy), zf = floorf(iz);
                float fy = iy - yf,    fz = iz - zf;
                int y0 = (int)yf, z0 = (int)zf;
                bool vy0 = (y0 >= 0)  & (y0 <  SPAT);
                bool vy1 = (y0 >= -1) & (y0 <  SPAT - 1);
                bool vz0 = (z0 >= 0)  & (z0 <  SPAT);
                bool vz1 = (z0 >= -1) & (z0 <  SPAT - 1);
                int y0c = min(max(y0, 0),     SPAT - 1);
                int y1c = min(max(y0 + 1, 0), SPAT - 1);
                int z0c = min(max(z0, 0),     SPAT - 1);
                int z1c = min(max(z0 + 1, 0), SPAT - 1);
                float wy0 = 1.0f - fy, wy1 = fy;
                float wz0 = 1.0f - fz, wz1 = fz;
                float w00 = wx * wz0 * wy0 * ((vz0 & vy0) ? 1.0f : 0.0f);
                float w01 = wx * wz0 * wy1 * ((vz0 & vy1) ? 1.0f : 0.0f);
                float w10 = wx * wz1 * wy0 * ((vz1 & vy0) ? 1.0f : 0.0f);
                float w11 = wx * wz1 * wy1 * ((vz1 & vy1) ? 1.0f : 0.0f);
                r = w00 * img[z0c * SPAT + y0c] + w01 * img[z0c * SPAT + y1c]
                  + w10 * img[z1c * SPAT + y0c] + w11 * img[z1c * SPAT + y1c];
            }
            vv[j] = r;
        }
        float4 v = make_float4(vv[0], vv[1], vv[2], vv[3]);
        if (!ovf) {
            stage[((size_t)t2 * IMG + (size_t)d * SPAT + h) * KSLOT
                  + (q - qlo)] = v;
        } else {   // pathological wide interval: compose straight into out
            *reinterpret_cast<float4*>(outp + (size_t)c_glob * PLANE
                + ((size_t)d * SPAT + h) * SPAT + 4 * q) = v;
        }
    }
}

// ---------------------------------------------------------------------------
// stream2: block = (d, cc) tile of 2304 float4 chunks. Prologue: coalesced
// linear load of the tile's staged slab values (96x3 float4 = 4.6 KB) and
// 96-dword row table into LDS; one barrier. Store loop: 9 unrolled
// iterations of {decode, 2 ds_reads, cndmask, float4 store} -- ZERO vmem
// loads, zero vmcnt dependencies, every 128B line written exactly once.
// This is the fill-kernel instruction mix plus cheap LDS/VALU work.
// ---------------------------------------------------------------------------
__global__ __launch_bounds__(256) void stream2_kernel(
        const float4* __restrict__ stage,
        const unsigned* __restrict__ rowinfo,
        float4* __restrict__ out) {
    __shared__ float4   sval[SPAT * KSLOT];   // 4608 B
    __shared__ unsigned rinf[SPAT];
    const int tid = (int)threadIdx.x;
    const int d   = blockIdx.x;               // 0..95
    const int cc  = blockIdx.y;               // 0..63 = b*32 + s*16 + ct
    const int b   = cc >> 5;
    const int s   = (cc >> 4) & 1;
    const int sb  = s * 2 + b;

    const float4* sp = stage
        + ((size_t)(sb * 16 + (cc & 15)) * IMG + (size_t)d * SPAT) * KSLOT;
    for (int i = tid; i < SPAT * KSLOT; i += 256) sval[i] = sp[i];
    if (tid < SPAT) rinf[tid] = rowinfo[(sb * SPAT + d) * SPAT + tid];
    __syncthreads();

    float4* op = out + (size_t)cc * (PLANE / 4) + (size_t)d * (IMG / 4);
    #pragma unroll
    for (int it = 0; it < 9; ++it) {
        const int tl = tid + 256 * it;        // 0..2303
        const unsigned h = (unsigned)tl / 24u;     // magic-mul
        const unsigned q = (unsigned)tl - h * 24u;
        const unsigned info = rinf[h];
        const unsigned qlo = info & 0xFFu;
        const unsigned qhi = (info >> 8) & 0xFFu;
        const bool ins = (q >= qlo) & (q <= qhi);  // empty rows: qlo=0xFF
        const bool ovf = (info & 0x10000u) != 0u;
        int slot = min(max((int)q - (int)qlo, 0), KSLOT - 1);
        float4 sv = sval[h * KSLOT + slot];
        float4 v = make_float4(ins ? sv.x : 0.f, ins ? sv.y : 0.f,
                               ins ? sv.z : 0.f, ins ? sv.w : 0.f);
        if (!(ins && ovf))                    // ovf interval chunks were
            op[tl] = v;                       // already written by prep2
    }
}

// ---------------------------------------------------------------------------
// Fallback (ws too small): R4 half-tile LDS-compose kernel, verbatim.
// ---------------------------------------------------------------------------
__global__ __launch_bounds__(256, 4) void fused4_kernel(
        const float* __restrict__ xin,
        const float* __restrict__ aff_in,
        float4* __restrict__ out) {
    __shared__ float4 tile[HCHUNK];
    const int tid = (int)threadIdx.x;
    const int dh2 = blockIdx.x;
    const int d   = dh2 >> 1;
    const int hh  = dh2 & 1;
    const int cc  = blockIdx.y;
    const int b   = cc >> 5;
    const int s   = (cc >> 4) & 1;
    const int sb  = s * 2 + b;

    float M[12];
    fold_affine(aff_in, sb, M);
    const float Mxw = M[0], Mxh = M[1], Mxd = M[2],  Mx0 = M[3];
    const float Myw = M[4], Myh = M[5], Myd = M[6],  My0 = M[7];
    const float Mzw = M[8], Mzh = M[9], Mzd = M[10], Mz0 = M[11];

    const float* img = xin + (size_t)cc * IMG;

    float tv[16];
    float bx = 0.f, by = 0.f, bz = 0.f;
    int   rr = 0, myq = 0, fqlo = 0, fqhi = -1;
    bool  act = false;
    if (tid < 2 * HROWS) {
        rr = tid >> 1;
        const int k = tid & 1;
        const int h = hh * HROWS + rr;
        const float fh = (float)h, fd = (float)d;
        bx = Mxh * fh + Mxd * fd + Mx0;
        by = Myh * fh + Myd * fd + My0;
        bz = Mzh * fh + Mzd * fd + Mz0;

        int wlo, whi;
        if (fabsf(Mxw) > 1e-6f) {
            float rMxw = 1.0f / Mxw;
            float w1 = (47.0f - bx) * rMxw;
            float w2 = (49.0f - bx) * rMxw;
            float wmin = fminf(w1, w2), wmax = fmaxf(w1, w2);
            wlo = max((int)ceilf(wmin), 0);
            whi = min((int)floorf(wmax), SPAT - 1);
        } else {
            bool in = fabsf(bx - 48.0f) < 1.0f;
            wlo = in ? 0 : 1;
            whi = in ? SPAT - 1 : 0;
        }
        const int qlo = wlo >> 2, qhi = whi >> 2;
        myq = qlo + k;
        if (wlo <= whi && myq <= qhi) {
            act = true;
            #pragma unroll
            for (int j = 0; j < 4; ++j) {
                float fw = (float)(4 * myq + j);
                float ix = Mxw * fw + bx;
                float wx = 1.0f - fabsf(ix - 48.0f);
                if (wx > 0.0f) {
                    float iy = Myw * fw + by;
                    float iz = Mzw * fw + bz;
                    int y0 = (int)floorf(iy), z0 = (int)floorf(iz);
                    int y0c = min(max(y0, 0),     SPAT - 1);
                    int y1c = min(max(y0 + 1, 0), SPAT - 1);
                    int z0c = min(max(z0, 0),     SPAT - 1);
                    int z1c = min(max(z0 + 1, 0), SPAT - 1);
                    tv[4*j+0] = img[z0c * SPAT + y0c];
                    tv[4*j+1] = img[z0c * SPAT + y1c];
                    tv[4*j+2] = img[z1c * SPAT + y0c];
                    tv[4*j+3] = img[z1c * SPAT + y1c];
                } else {
                    tv[4*j+0] = 0.f; tv[4*j+1] = 0.f;
                    tv[4*j+2] = 0.f; tv[4*j+3] = 0.f;
                }
            }
        }
        if (k == 1 && wlo <= whi) { fqlo = qlo + 2; fqhi = qhi; }
    }

    const float4 z4 = make_float4(0.f, 0.f, 0.f, 0.f);
    #pragma unroll
    for (int i = tid; i < HCHUNK; i += 256) tile[i] = z4;

    __syncthreads();

    if (act) {
        float vv[4];
        #pragma unroll
        for (int j = 0; j < 4; ++j) {
            float fw = (float)(4 * myq + j);
            float ix = Mxw * fw + bx;
            float wx = 1.0f - fabsf(ix - 48.0f);
            float r = 0.0f;
            if (wx > 0.0f) {
                float iy = Myw * fw + by;
                float iz = Mzw * fw + bz;
                float yf = floorf(iy), zf = floorf(iz);
                float fy = iy - yf,    fz = iz - zf;
                int y0 = (int)yf, z0 = (int)zf;
                bool vy0 = (y0 >= 0)  & (y0 <  SPAT);
                bool vy1 = (y0 >= -1) & (y0 <  SPAT - 1);
                bool vz0 = (z0 >= 0)  & (z0 <  SPAT);
                bool vz1 = (z0 >= -1) & (z0 <  SPAT - 1);
                float wy0 = 1.0f - fy, wy1 = fy;
                float wz0 = 1.0f - fz, wz1 = fz;
                float w00 = wx * wz0 * wy0 * ((vz0 & vy0) ? 1.0f : 0.0f);
                float w01 = wx * wz0 * wy1 * ((vz0 & vy1) ? 1.0f : 0.0f);
                float w10 = wx * wz1 * wy0 * ((vz1 & vy0) ? 1.0f : 0.0f);
                float w11 = wx * wz1 * wy1 * ((vz1 & vy1) ? 1.0f : 0.0f);
                r = w00 * tv[4*j+0] + w01 * tv[4*j+1]
                  + w10 * tv[4*j+2] + w11 * tv[4*j+3];
            }
            vv[j] = r;
        }
        tile[rr * 24 + myq] = make_float4(vv[0], vv[1], vv[2], vv[3]);
    }
    for (int q = fqlo; q <= fqhi; ++q) {
        float vv[4];
        #pragma unroll
        for (int j = 0; j < 4; ++j) {
            float fw = (float)(4 * q + j);
            float ix = Mxw * fw + bx;
            float wx = 1.0f - fabsf(ix - 48.0f);
            float r = 0.0f;
            if (wx > 0.0f) {
                float iy = Myw * fw + by;
                float iz = Mzw * fw + bz;
                float yf = floorf(iy), zf = floorf(iz);
                float fy = iy - yf,    fz = iz - zf;
                int y0 = (int)yf, z0 = (int)zf;
                bool vy0 = (y0 >= 0)  & (y0 <  SPAT);
                bool vy1 = (y0 >= -1) & (y0 <  SPAT - 1);
                bool vz0 = (z0 >= 0)  & (z0 <  SPAT);
                bool vz1 = (z0 >= -1) & (z0 <  SPAT - 1);
                int y0c = min(max(y0, 0),     SPAT - 1);
                int y1c = min(max(y0 + 1, 0), SPAT - 1);
                int z0c = min(max(z0, 0),     SPAT - 1);
                int z1c = min(max(z0 + 1, 0), SPAT - 1);
                float wy0 = 1.0f - fy, wy1 = fy;
                float wz0 = 1.0f - fz, wz1 = fz;
                float w00 = wx * wz0 * wy0 * ((vz0 & vy0) ? 1.0f : 0.0f);
                float w01 = wx * wz0 * wy1 * ((vz0 & vy1) ? 1.0f : 0.0f);
                float w10 = wx * wz1 * wy0 * ((vz1 & vy0) ? 1.0f : 0.0f);
                float w11 = wx * wz1 * wy1 * ((vz1 & vy1) ? 1.0f : 0.0f);
                r = w00 * img[z0c * SPAT + y0c] + w01 * img[z0c * SPAT + y1c]
                  + w10 * img[z1c * SPAT + y0c] + w11 * img[z1c * SPAT + y1c];
            }
            vv[j] = r;
        }
        tile[rr * 24 + q] = make_float4(vv[0], vv[1], vv[2], vv[3]);
    }

    __syncthreads();

    float4* op = out + ((size_t)cc * (PLANE / 4) + (size_t)d * (IMG / 4)
                        + (size_t)hh * HCHUNK);
    #pragma unroll
    for (int i = tid; i < HCHUNK; i += 256) op[i] = tile[i];
}

extern "C" void kernel_launch(void* const* d_in, const int* in_sizes, int n_in,
                              void* d_out, int out_size, void* d_ws, size_t ws_size,
                              hipStream_t stream) {
    const float* x   = (const float*)d_in[0];   // [2,32,96,96] fp32
    const float* aff = (const float*)d_in[1];   // [2,2,4,4]    fp32
    float* out = (float*)d_out;                 // [2,32,96,96,96] fp32

    if (d_ws != nullptr && ws_size >= WS_NEED) {
        float4*   stage   = (float4*)d_ws;
        unsigned* rowinfo = (unsigned*)((char*)d_ws + STAGE_BYTES);
        // 1) prep2: 589,824 threads, latency-hidden gathers, compact staging
        prep2_kernel<<<2304, 256, 0, stream>>>(x, aff, stage, rowinfo, out);
        // 2) stream2: store-pure pass, slab values served from LDS
        dim3 sgrid(SPAT, 64);
        stream2_kernel<<<sgrid, 256, 0, stream>>>(stage, rowinfo, (float4*)out);
    } else {
        dim3 grid(2 * SPAT, 64);
        fused4_kernel<<<grid, 256, 0, stream>>>(x, aff, (float4*)out);
    }
}